// Round 3
// baseline (700.363 us; speedup 1.0000x reference)
//
#include <hip/hip_runtime.h>
#include <hip/hip_bf16.h>

// Problem: B=8, N=1024, C=256, R=16
//   qh = q @ Wq^T + bq ; kh = k @ Wk^T + bk       (B,N,C)
//   scores = qh @ kh^T / 16                        (B,N,N)
//   out[b,r,i,j] = scores[b,i,j] * R_map[i,j,r]    (B,R,N,N) fp32
//
// Stage 1: proj_kernel -> qh,kh as bf16 in d_ws (4 MiB each).
// Stage 2: score_mul_kernel. R0-R2 post-mortem: three different store
//          patterns all ~315-330 us => NOT store-pattern-bound. Invariant
//          was 64 KiB LDS -> 2 blocks/CU -> 2 waves/SIMD, with a serial
//          ds_read -> 16 diverged R-loads -> stores chain per row:
//          latency-bound. This version halves the j-extent per block
//          (grid z = j-half) so LDS = 16x512 fp32 = 32 KiB -> 4 blocks/CU,
//          4 waves/SIMD, 1024 blocks all resident. MFMA tiles stay full
//          16-row. Multiply keeps only 16 R-registers live (r-group chunks)
//          to stay under 128 VGPR for 16 waves/CU.
//          XCD: linear = itile + 64*b + 512*h; b-stride 64 => %8==0 => the
//          8 b-sharers of each R_map slab share one XCD L2 (R fetched once).

typedef float  floatx4 __attribute__((ext_vector_type(4)));
typedef short  shortx8 __attribute__((ext_vector_type(8)));

__device__ __forceinline__ short f2bf(float f) {
    // round-to-nearest-even f32 -> bf16 (inputs are finite; no NaN handling)
    unsigned int u = __builtin_bit_cast(unsigned int, f);
    u += 0x7fffu + ((u >> 16) & 1u);
    return (short)(u >> 16);
}

// ---------------- Stage 1: Q/K projection, fp32 in -> bf16 out ----------------
// grid (512, 4, 2), block 64 (one wave). z=0: Q, z=1: K.
// Tile: 16 rows x 64 cols per wave, K=256 in 8 MFMA steps x 4 col-tiles.
__global__ __launch_bounds__(64) void proj_kernel(
    const float* __restrict__ Xq, const float* __restrict__ Wq, const float* __restrict__ bq,
    const float* __restrict__ Xk, const float* __restrict__ Wk, const float* __restrict__ bk,
    short* __restrict__ qh, short* __restrict__ kh)
{
    const float* X; const float* W; const float* bias; short* outp;
    if (blockIdx.z == 0) { X = Xq; W = Wq; bias = bq; outp = qh; }
    else                 { X = Xk; W = Wk; bias = bk; outp = kh; }

    const int lane  = threadIdx.x;
    const int row16 = lane & 15;
    const int quad  = lane >> 4;
    const int m0 = blockIdx.x * 16;   // row tile in (B*N)=8192
    const int c0 = blockIdx.y * 64;   // col tile in C=256

    const float* xr = X + (size_t)(m0 + row16) * 256 + quad * 8;
    const float* wr = W + (size_t)(c0 + row16) * 256 + quad * 8;

    floatx4 acc[4];
#pragma unroll
    for (int nt = 0; nt < 4; nt++) acc[nt] = floatx4{0.f, 0.f, 0.f, 0.f};

#pragma unroll
    for (int k = 0; k < 256; k += 32) {
        float4 a0 = *(const float4*)(xr + k);
        float4 a1 = *(const float4*)(xr + k + 4);
        shortx8 af = { f2bf(a0.x), f2bf(a0.y), f2bf(a0.z), f2bf(a0.w),
                       f2bf(a1.x), f2bf(a1.y), f2bf(a1.z), f2bf(a1.w) };
#pragma unroll
        for (int nt = 0; nt < 4; nt++) {
            const float* w0 = wr + (size_t)nt * 16 * 256 + k;
            float4 b0 = *(const float4*)(w0);
            float4 b1 = *(const float4*)(w0 + 4);
            shortx8 bf = { f2bf(b0.x), f2bf(b0.y), f2bf(b0.z), f2bf(b0.w),
                           f2bf(b1.x), f2bf(b1.y), f2bf(b1.z), f2bf(b1.w) };
            acc[nt] = __builtin_amdgcn_mfma_f32_16x16x32_bf16(af, bf, acc[nt], 0, 0, 0);
        }
    }

    // C/D layout: col = lane&15 (c within tile), row = quad*4+reg (m)
#pragma unroll
    for (int nt = 0; nt < 4; nt++) {
        const int c = c0 + nt * 16 + row16;
        const float bv = bias[c];
#pragma unroll
        for (int r = 0; r < 4; r++) {
            const int m = m0 + quad * 4 + r;
            outp[(size_t)m * 256 + c] = f2bf(acc[nt][r] + bv);
        }
    }
}

// ---------------- Stage 2: fused QK^T * (1/16) * R_map -> out ----------------
// grid (64, 8, 2): x = i-tile (16 rows), y = b, z = j-half (512 cols).
// block 256 = 4 waves. LDS 32 KiB -> 4 blocks/CU, 16 waves/CU.
// Compute: wave w computes scores[i0..i0+15][h*512 + w*128 .. +128)
//          (8 MFMA col-tiles, A-frags in regs) -> LDS [16][512].
// Multiply: thread t: row-half ih = t>>7, local j = (t&127)*4. Per i-row:
//          4 r-group chunks of {4 coalesced-ish R loads + 4 nt dwordx4
//          stores}; each wave-store is 1 KiB contiguous.
__global__ __launch_bounds__(256, 4) void score_mul_kernel(
    const short* __restrict__ qh, const short* __restrict__ kh,
    const float* __restrict__ Rm, float* __restrict__ out)
{
    const int itile = blockIdx.x;
    const int b     = blockIdx.y;
    const int h     = blockIdx.z;
    const int i0    = itile * 16;

    const int tid   = threadIdx.x;
    const int w     = tid >> 6;
    const int lane  = tid & 63;
    const int row16 = lane & 15;
    const int quad  = lane >> 4;

    __shared__ float s_lds[16 * 512];   // 32 KiB

    // ---- compute phase ----
    const short* qbase = qh + ((size_t)(b * 1024 + i0 + row16)) * 256 + quad * 8;
    shortx8 a[8];
#pragma unroll
    for (int ks = 0; ks < 8; ks++) a[ks] = *(const shortx8*)(qbase + ks * 32);

    const short* kb = kh + ((size_t)(b * 1024 + h * 512 + w * 128 + row16)) * 256 + quad * 8;
    const float inv = 0.0625f;  // 1/sqrt(256)

#pragma unroll 2
    for (int jt = 0; jt < 8; jt++) {
        floatx4 acc = {0.f, 0.f, 0.f, 0.f};
        const short* kr = kb + (size_t)jt * 16 * 256;
#pragma unroll
        for (int ks = 0; ks < 8; ks++) {
            shortx8 bfr = *(const shortx8*)(kr + ks * 32);
            acc = __builtin_amdgcn_mfma_f32_16x16x32_bf16(a[ks], bfr, acc, 0, 0, 0);
        }
        // C/D layout: col = lane&15 (j within tile), row = quad*4+reg (i)
#pragma unroll
        for (int r = 0; r < 4; r++)
            s_lds[(quad * 4 + r) * 512 + w * 128 + jt * 16 + row16] = acc[r] * inv;
    }
    __syncthreads();

    // ---- multiply phase ----
    const int ih = tid >> 7;            // row half: 0 -> rows 0..7, 1 -> rows 8..15
    const int jl = (tid & 127) * 4;     // local j in [0, 512)
    const int j  = h * 512 + jl;        // global j
    const size_t NN = (size_t)1024 * 1024;
    float* ob = out + (size_t)(b * 16) * NN + j;

    for (int il = 0; il < 8; il++) {
        const int ilocal = ih * 8 + il;
        const int i = i0 + ilocal;
        floatx4 s4 = *(const floatx4*)&s_lds[ilocal * 512 + jl];
        const float* rp = Rm + ((size_t)i * 1024 + j) * 16;
        float* op = ob + (size_t)i * 1024;

#pragma unroll
        for (int rg = 0; rg < 4; rg++) {
            // R[i, j+jo, rg*4 .. rg*4+3] for jo=0..3  (16 regs live)
            floatx4 q0 = *(const floatx4*)(rp + 0  + rg * 4);
            floatx4 q1 = *(const floatx4*)(rp + 16 + rg * 4);
            floatx4 q2 = *(const floatx4*)(rp + 32 + rg * 4);
            floatx4 q3 = *(const floatx4*)(rp + 48 + rg * 4);
#pragma unroll
            for (int rs = 0; rs < 4; rs++) {
                floatx4 v = { q0[rs] * s4[0], q1[rs] * s4[1],
                              q2[rs] * s4[2], q3[rs] * s4[3] };
                __builtin_nontemporal_store(v, (floatx4*)(op + (size_t)(rg * 4 + rs) * NN));
            }
        }
    }
}

extern "C" void kernel_launch(void* const* d_in, const int* in_sizes, int n_in,
                              void* d_out, int out_size, void* d_ws, size_t ws_size,
                              hipStream_t stream) {
    const float* q   = (const float*)d_in[0];  // (8,1024,256)
    const float* k   = (const float*)d_in[1];  // (8,1024,256)
    const float* Wq  = (const float*)d_in[2];  // (256,256)
    const float* bq  = (const float*)d_in[3];  // (256)
    const float* Wk  = (const float*)d_in[4];  // (256,256)
    const float* bk  = (const float*)d_in[5];  // (256)
    const float* Rm  = (const float*)d_in[6];  // (1024,1024,16)
    float* out = (float*)d_out;                // (8,16,1024,1024)

    short* qh = (short*)d_ws;                         // 8192*256 bf16 = 4 MiB
    short* kh = (short*)d_ws + (size_t)8192 * 256;    // next 4 MiB

    dim3 pgrid(512, 4, 2);
    proj_kernel<<<pgrid, 64, 0, stream>>>(q, Wq, bq, k, Wk, bk, qh, kh);

    dim3 sgrid(64, 8, 2);
    score_mul_kernel<<<sgrid, 256, 0, stream>>>(qh, kh, Rm, out);
}